// Round 8
// baseline (496.828 us; speedup 1.0000x reference)
//
#include <hip/hip_runtime.h>

typedef unsigned short u16;
typedef unsigned int   u32;
typedef float  f32x4  __attribute__((ext_vector_type(4)));
typedef __bf16 bf16x8 __attribute__((ext_vector_type(8)));
typedef u32    u32x4  __attribute__((ext_vector_type(4)));
typedef u32    u32x2  __attribute__((ext_vector_type(2)));

#define Bb  8
#define Nn  1024
#define Dd  256
#define Hh  8
#define HDd 32
#define CAP 96

__device__ __forceinline__ float bf2f(u16 s){
  u32 u = ((u32)s) << 16; float f; __builtin_memcpy(&f, &u, 4); return f;
}
__device__ __forceinline__ u16 f2bf(float f){
  u32 u; __builtin_memcpy(&u, &f, 4);
  u = (u + 0x7fffu + ((u >> 16) & 1u)) >> 16;
  return (u16)u;
}
__device__ __forceinline__ f32x4 mfma16(bf16x8 a, bf16x8 b, f32x4 c){
  return __builtin_amdgcn_mfma_f32_16x16x32_bf16(a, b, c, 0, 0, 0);
}
__device__ __forceinline__ bf16x8 ld_bf8(const u16* p){
  u32x4 u = *(const u32x4*)p; bf16x8 r; __builtin_memcpy(&r, &u, 16); return r;
}

// ---------------- f32 -> bf16 convert ----------------
__global__ void f32_to_bf16(const float* __restrict__ src, u16* __restrict__ dst, int n){
  int i = (blockIdx.x * 256 + threadIdx.x) * 4;
  if (i < n){
    f32x4 v = *(const f32x4*)(src + i);
    u32x2 p;
    p[0] = (u32)f2bf(v[0]) | ((u32)f2bf(v[1]) << 16);
    p[1] = (u32)f2bf(v[2]) | ((u32)f2bf(v[3]) << 16);
    *(u32x2*)(dst + i) = p;
  }
}

// ---------------- 4-weight convert (Wq,Wk,Wv,Wo -> contiguous bf16) ----------------
__global__ void conv_w4(const float* __restrict__ wq, const float* __restrict__ wk,
                        const float* __restrict__ wv, const float* __restrict__ wo,
                        u16* __restrict__ dst){
  int g = blockIdx.x * 256 + threadIdx.x;      // 0..196607
  int sec = g / 49152, off = (g - sec * 49152) * 4;
  const float* src = (sec == 0 ? wq : sec == 1 ? wk : sec == 2 ? wv : wo);
  f32x4 v = *(const f32x4*)(src + off);
  u32x2 p;
  p[0] = (u32)f2bf(v[0]) | ((u32)f2bf(v[1]) << 16);
  p[1] = (u32)f2bf(v[2]) | ((u32)f2bf(v[3]) << 16);
  *(u32x2*)(dst + sec * 196608 + off) = p;
}

// ---------------- bias concat: bqkv[l][z*256+j] = (bq|bk|bv)[l][j] ----------------
__global__ void bias_concat(const float* __restrict__ bq, const float* __restrict__ bk,
                            const float* __restrict__ bv, float* __restrict__ bqkv){
  int t = threadIdx.x;   // 256
  for (int l = 0; l < 3; ++l){
    bqkv[l*768 +       t] = bq[l*256 + t];
    bqkv[l*768 + 256 + t] = bk[l*256 + t];
    bqkv[l*768 + 512 + t] = bv[l*256 + t];
  }
}

// ---------------- adj -> bitmask ----------------
__global__ void adj_to_bits(const float* __restrict__ adj, u32* __restrict__ bits){
  int w = blockIdx.x * 256 + threadIdx.x;        // word over [1024][32]
  const float* p = adj + (long)w * 32;
  u32 m = 0;
  #pragma unroll
  for (int t = 0; t < 32; t += 4){
    f32x4 v = *(const f32x4*)(p + t);
    if (v[0] != 0.f) m |= 1u << (t+0);
    if (v[1] != 0.f) m |= 1u << (t+1);
    if (v[2] != 0.f) m |= 1u << (t+2);
    if (v[3] != 0.f) m |= 1u << (t+3);
  }
  bits[w] = m;
}

// ---------------- neighbor list build (CSR, capacity CAP) ----------------
__global__ __launch_bounds__(256) void nbr_build(const u32* __restrict__ bits,
                                                 u16* __restrict__ idx, int* __restrict__ cnt){
  int i = blockIdx.x * 256 + threadIdx.x;        // grid 4
  int c = 0;
  for (int w = 0; w < 32; ++w){
    u32 wd = bits[i*32 + w];
    while (wd){
      int bi = __ffs(wd) - 1; wd &= wd - 1;
      if (c < CAP) idx[(long)i*CAP + c] = (u16)(w*32 + bi);
      ++c;
    }
  }
  cnt[i] = (c < CAP) ? c : CAP;
}

// ---------------- MFMA GEMM: C[m][n] = sum_k A[m][k]*Bt[n][k] (+bias) ----------------
// VALIDATED (R4-R6); sbc = per-blockz bias stride (0 for all legacy call sites).
template<bool HBC, bool HBR, bool OF, bool OB>
__global__ __launch_bounds__(256,2) void gemm_bt(
    const u16* __restrict__ A, int lda, long sA,
    const u16* __restrict__ Bt, int ldb, long sB,
    float* __restrict__ Cf, u16* __restrict__ Cb, int ldc, long sC,
    int K, const float* __restrict__ bc, long sbc, const float* __restrict__ br)
{
  __shared__ u16 As[128][40];
  __shared__ u16 Bs[128][40];
  const int bz = blockIdx.z;
  const u16* Ap = A + (long)bz * sA;
  const u16* Bp = Bt + (long)bz * sB;
  const long co = (long)bz * sC;
  const int m0 = blockIdx.y * 128, n0 = blockIdx.x * 128;
  const int tid = threadIdx.x, wave = tid >> 6, lane = tid & 63;
  const int arow = lane & 15, agrp = lane >> 4;
  const int wr = (wave >> 1) * 64, wc = (wave & 1) * 64;
  const int srow = tid >> 1, sch = (tid & 1) * 16;
  const u16* ga = Ap + (long)(m0 + srow) * lda + sch;
  const u16* gb = Bp + (long)(n0 + srow) * ldb + sch;
  f32x4 acc[4][4] = {};
  for (int kb = 0; kb < K; kb += 32){
    u32x4 a0 = *(const u32x4*)ga; u32x4 a1 = *(const u32x4*)(ga + 8);
    u32x4 b0 = *(const u32x4*)gb; u32x4 b1 = *(const u32x4*)(gb + 8);
    __syncthreads();
    *(u32x4*)&As[srow][sch] = a0; *(u32x4*)&As[srow][sch + 8] = a1;
    *(u32x4*)&Bs[srow][sch] = b0; *(u32x4*)&Bs[srow][sch + 8] = b1;
    __syncthreads();
    ga += 32; gb += 32;
    bf16x8 af[4], bv[4];
    #pragma unroll
    for (int f = 0; f < 4; ++f){
      af[f] = ld_bf8(&As[wr + f*16 + arow][agrp*8]);
      bv[f] = ld_bf8(&Bs[wc + f*16 + arow][agrp*8]);
    }
    #pragma unroll
    for (int fm = 0; fm < 4; ++fm)
      #pragma unroll
      for (int fn = 0; fn < 4; ++fn)
        acc[fm][fn] = mfma16(af[fm], bv[fn], acc[fm][fn]);
  }
  #pragma unroll
  for (int fm = 0; fm < 4; ++fm){
    #pragma unroll
    for (int fn = 0; fn < 4; ++fn){
      int j = n0 + wc + fn*16 + arow;
      float badd = 0.f;
      if (HBC) badd = bc[(long)bz*sbc + j];
      #pragma unroll
      for (int r = 0; r < 4; ++r){
        int i = m0 + wr + fm*16 + agrp*4 + r;
        float v = acc[fm][fn][r] + badd;
        if (HBR) v += br[i];
        long idx = co + (long)i * ldc + j;
        if (OF) Cf[idx] = v;
        if (OB) Cb[idx] = f2bf(v);
      }
    }
  }
}

// ---------------- sparse attention: wave per (b,row); lane = neighbor slot ----------------
__global__ __launch_bounds__(256) void attn_sparse(
    const u16* __restrict__ qkv,          // [B*N][768] bf16: q|k|v
    u16* __restrict__ ob,                 // [B*N][256] bf16
    const u16* __restrict__ idxg, const int* __restrict__ cntg,
    float* __restrict__ amv)              // [B*N][CAP] f32 (slots < cnt valid)
{
  __shared__ float qs[4][256];            // q rows, pre-scaled
  __shared__ float E[4][CAP][8];          // normalized exp per (slot, head)
  __shared__ u16   idxl[4][CAP];
  __shared__ int   cntl[4];
  const int b = blockIdx.y, i0 = blockIdx.x * 4, tid = threadIdx.x;
  const int w = tid >> 6, lane = tid & 63;
  const float SCALE = 0.17677669529663687f;   // 1/sqrt(32)

  { int e = tid * 4, rr = e >> 8, c = e & 255;
    const u16* src = qkv + ((long)(b*Nn + i0 + rr)) * 768 + c;
    u32x2 uv = *(const u32x2*)src;
    qs[rr][c+0] = SCALE * bf2f((u16)(uv[0] & 0xffff));
    qs[rr][c+1] = SCALE * bf2f((u16)(uv[0] >> 16));
    qs[rr][c+2] = SCALE * bf2f((u16)(uv[1] & 0xffff));
    qs[rr][c+3] = SCALE * bf2f((u16)(uv[1] >> 16)); }
  for (int s = tid; s < 4*CAP; s += 256){     // FIX(R7): stride loop, 384 slots > 256 thr
    int rr = s / CAP, ss = s - rr*CAP;
    idxl[rr][ss] = idxg[(long)(i0 + rr)*CAP + ss];
  }
  if (tid < 4) cntl[tid] = cntg[i0 + tid];
  __syncthreads();

  const int i = i0 + w;
  const int cnt = cntl[w];
  const bool act1 = lane < cnt;
  const bool has2 = cnt > 64;                  // wave-uniform, rare
  const bool act2 = has2 && (lane + 64 < cnt);
  const int j1 = act1 ? idxl[w][lane] : 0;
  const int j2 = act2 ? idxl[w][lane + 64] : 0;

  float sc[8] = {}, sc2[8] = {};
  { const u16* kp = qkv + ((long)(b*Nn + j1)) * 768 + 256;
    #pragma unroll
    for (int c = 0; c < 32; ++c){
      bf16x8 kv = ld_bf8(kp + c*8);
      const float* qq = &qs[w][c*8];
      float p = qq[0]*(float)kv[0] + qq[1]*(float)kv[1] + qq[2]*(float)kv[2] + qq[3]*(float)kv[3]
              + qq[4]*(float)kv[4] + qq[5]*(float)kv[5] + qq[6]*(float)kv[6] + qq[7]*(float)kv[7];
      sc[c>>2] += p;
    }
  }
  if (has2){
    const u16* kp = qkv + ((long)(b*Nn + j2)) * 768 + 256;
    #pragma unroll
    for (int c = 0; c < 32; ++c){
      bf16x8 kv = ld_bf8(kp + c*8);
      const float* qq = &qs[w][c*8];
      float p = qq[0]*(float)kv[0] + qq[1]*(float)kv[1] + qq[2]*(float)kv[2] + qq[3]*(float)kv[3]
              + qq[4]*(float)kv[4] + qq[5]*(float)kv[5] + qq[6]*(float)kv[6] + qq[7]*(float)kv[7];
      sc2[c>>2] += p;
    }
  }
  // ---- per-head softmax across lanes; E = normalized weights ----
  float a1 = 0.f, a2 = 0.f;
  #pragma unroll
  for (int h = 0; h < 8; ++h){
    float m = act1 ? sc[h] : -3.0e38f;
    if (act2) m = fmaxf(m, sc2[h]);
    #pragma unroll
    for (int off = 32; off; off >>= 1) m = fmaxf(m, __shfl_xor(m, off, 64));
    float e1 = act1 ? __expf(sc[h] - m) : 0.f;
    float e2 = act2 ? __expf(sc2[h] - m) : 0.f;
    float l = e1 + e2;
    #pragma unroll
    for (int off = 32; off; off >>= 1) l += __shfl_xor(l, off, 64);
    float invl = 1.f / l;
    e1 *= invl; e2 *= invl;
    if (act1) E[w][lane][h] = e1;
    if (act2) E[w][lane + 64][h] = e2;
    a1 += e1; a2 += e2;
  }
  if (act1) amv[((long)(b*Nn + i))*CAP + lane]      = a1 * 0.125f;
  if (act2) amv[((long)(b*Nn + i))*CAP + lane + 64] = a2 * 0.125f;
  __syncthreads();
  // ---- PV: lane owns 4 output dims; loop neighbors with coalesced V reads ----
  const int d0 = lane * 4, h = lane >> 3;
  f32x4 acc = {0.f, 0.f, 0.f, 0.f};
  for (int s = 0; s < cnt; ++s){
    int j = idxl[w][s];
    float ev = E[w][s][h];
    u32x2 vv = *(const u32x2*)(qkv + ((long)(b*Nn + j)) * 768 + 512 + d0);
    acc[0] += ev * bf2f((u16)(vv[0] & 0xffff));
    acc[1] += ev * bf2f((u16)(vv[0] >> 16));
    acc[2] += ev * bf2f((u16)(vv[1] & 0xffff));
    acc[3] += ev * bf2f((u16)(vv[1] >> 16));
  }
  u32x2 pb;
  pb[0] = (u32)f2bf(acc[0]) | ((u32)f2bf(acc[1]) << 16);
  pb[1] = (u32)f2bf(acc[2]) | ((u32)f2bf(acc[3]) << 16);
  *(u32x2*)(ob + ((long)(b*Nn + i)) * 256 + d0) = pb;
}

// ---------------- sparse chain 1: P1[b][i][:] = sum_s amv1[i][s] * am0_row[idx[i][s]] ----------------
__global__ __launch_bounds__(256) void sp_gemm1(
    const float* __restrict__ amv1, const float* __restrict__ amv0,
    const u16* __restrict__ idxg, const int* __restrict__ cntg,
    u16* __restrict__ P1)                 // [B*N][1024] bf16
{
  __shared__ float accum[1024];
  __shared__ u16 idxl[CAP];
  __shared__ float v1[CAP];
  const int b = blockIdx.y, i = blockIdx.x, tid = threadIdx.x;
  { f32x4 z = {0.f,0.f,0.f,0.f}; *(f32x4*)&accum[tid*4] = z; }
  const int cnt = cntg[i];
  if (tid < CAP){
    idxl[tid] = idxg[(long)i*CAP + tid];
    v1[tid]   = amv1[((long)(b*Nn + i))*CAP + tid];
  }
  __syncthreads();
  const int npairs = cnt * 64;
  for (int p = tid; p < npairs; p += 256){
    int s = p >> 6, t = p & 63;
    int j = idxl[s];
    int cj = cntg[j];
    float vs = v1[s];
    if (t < cj){
      int col = idxg[(long)j*CAP + t];
      atomicAdd(&accum[col], vs * amv0[((long)(b*Nn + j))*CAP + t]);
    }
    if (cj > 64 && t + 64 < cj){
      int col = idxg[(long)j*CAP + t + 64];
      atomicAdd(&accum[col], vs * amv0[((long)(b*Nn + j))*CAP + t + 64]);
    }
  }
  __syncthreads();
  int c0 = tid * 4;
  u32x2 pb;
  pb[0] = (u32)f2bf(accum[c0])   | ((u32)f2bf(accum[c0+1]) << 16);
  pb[1] = (u32)f2bf(accum[c0+2]) | ((u32)f2bf(accum[c0+3]) << 16);
  *(u32x2*)(P1 + ((long)(b*Nn + i))*1024 + c0) = pb;
}

// ---------------- sparse chain 2: out[b][i][:] = sum_s amv2[i][s] * P1[b][idx[i][s]][:] ----------------
__global__ __launch_bounds__(256) void sp_gemm2(
    const float* __restrict__ amv2, const u16* __restrict__ P1,
    const u16* __restrict__ idxg, const int* __restrict__ cntg,
    float* __restrict__ out)              // [B*N][1024] f32 (d_out atten)
{
  __shared__ u16 idxl[CAP];
  __shared__ float v2[CAP];
  const int b = blockIdx.y, i = blockIdx.x, tid = threadIdx.x;
  const int cnt = cntg[i];
  if (tid < CAP){
    idxl[tid] = idxg[(long)i*CAP + tid];
    v2[tid]   = amv2[((long)(b*Nn + i))*CAP + tid];
  }
  __syncthreads();
  f32x4 acc = {0.f, 0.f, 0.f, 0.f};
  const int c0 = tid * 4;
  for (int s = 0; s < cnt; ++s){
    int j = idxl[s];
    float ev = v2[s];
    u32x2 vv = *(const u32x2*)(P1 + ((long)(b*Nn + j))*1024 + c0);
    acc[0] += ev * bf2f((u16)(vv[0] & 0xffff));
    acc[1] += ev * bf2f((u16)(vv[0] >> 16));
    acc[2] += ev * bf2f((u16)(vv[1] & 0xffff));
    acc[3] += ev * bf2f((u16)(vv[1] >> 16));
  }
  *(f32x4*)(out + ((long)(b*Nn + i))*1024 + c0) = acc;
}

// ---------------- residual + layernorm ----------------
__global__ __launch_bounds__(256) void ln_kernel(
    const float* __restrict__ hin, const float* __restrict__ y,
    float* __restrict__ hout, u16* __restrict__ hb, float* __restrict__ outf,
    const float* __restrict__ g, const float* __restrict__ be)
{
  int row  = blockIdx.x * 4 + (threadIdx.x >> 6);
  int lane = threadIdx.x & 63;
  f32x4 v = *(const f32x4*)(hin + (long)row*Dd + lane*4)
          + *(const f32x4*)(y   + (long)row*Dd + lane*4);
  float s = v[0] + v[1] + v[2] + v[3];
  #pragma unroll
  for (int off = 32; off; off >>= 1) s += __shfl_xor(s, off, 64);
  float mu = s * (1.f/256.f);
  f32x4 d = v - mu;
  float q2 = d[0]*d[0] + d[1]*d[1] + d[2]*d[2] + d[3]*d[3];
  #pragma unroll
  for (int off = 32; off; off >>= 1) q2 += __shfl_xor(q2, off, 64);
  float rs = rsqrtf(q2 * (1.f/256.f) + 1e-5f);
  f32x4 ov;
  #pragma unroll
  for (int p = 0; p < 4; ++p)
    ov[p] = d[p] * rs * g[lane*4 + p] + be[lane*4 + p];
  *(f32x4*)(hout + (long)row*Dd + lane*4) = ov;
  if (hb){
    u32x2 pb;
    pb[0] = (u32)f2bf(ov[0]) | ((u32)f2bf(ov[1]) << 16);
    pb[1] = (u32)f2bf(ov[2]) | ((u32)f2bf(ov[3]) << 16);
    *(u32x2*)(hb + (long)row*Dd + lane*4) = pb;
  }
  if (outf)
    *(f32x4*)(outf + (long)row*Dd + lane*4) = ov;
}

extern "C" void kernel_launch(void* const* d_in, const int* in_sizes, int n_in,
                              void* d_out, int out_size, void* d_ws, size_t ws_size,
                              hipStream_t stream)
{
  (void)in_sizes; (void)n_in; (void)out_size; (void)ws_size;
  const float* x   = (const float*)d_in[0];
  const float* adj = (const float*)d_in[1];
  const float* W0  = (const float*)d_in[2];
  const float* Wq  = (const float*)d_in[3];
  const float* bq  = (const float*)d_in[4];
  const float* Wk  = (const float*)d_in[5];
  const float* bk  = (const float*)d_in[6];
  const float* Wv  = (const float*)d_in[7];
  const float* bv  = (const float*)d_in[8];
  const float* Wo  = (const float*)d_in[9];
  const float* bo  = (const float*)d_in[10];
  const float* gm  = (const float*)d_in[11];
  const float* bt  = (const float*)d_in[12];
  float* outf  = (float*)d_out;                 // f32 h region [8,1024,256]
  float* outat = outf + (long)Bb * Nn * Dd;     // f32 atten region [8,1024,1024]

  // ---- workspace (~67MB < proven 92MB) ----
  char* w = (char*)d_ws;
  u16* W0b  = (u16*)w; w += 131072;
  u16* Wqb  = (u16*)w; w += 393216;             // Wq|Wk|Wv|Wo contiguous (conv_w4)
  u16* Wkb  = (u16*)w; w += 393216;
  u16* Wvb  = (u16*)w; w += 393216;
  u16* Wob  = (u16*)w; w += 393216;
  float* bqkv = (float*)w; w += 9216;           // [3][768]
  u32* bitsg = (u32*)w; w += 131072;
  u16* idxg  = (u16*)w; w += 1024*CAP*2;        // 192KB
  int* cntg  = (int*)w; w += 4096;
  u16* xb  = (u16*)w; w += 4194304;
  u16* hb  = (u16*)w; w += 4194304;
  u16* qkv = (u16*)w; w += (long)Bb*Nn*768*2;   // 12MB
  u16* ob  = (u16*)w; w += 4194304;
  float* hbuf = (float*)w; w += 8388608;
  float* ybuf = (float*)w; w += 8388608;
  float* amv0 = (float*)w; w += (long)Bb*Nn*CAP*4;  // 3MB each
  float* amv1 = (float*)w; w += (long)Bb*Nn*CAP*4;
  float* amv2 = (float*)w; w += (long)Bb*Nn*CAP*4;
  u16* P1   = (u16*)w; w += 16777216;           // [8][1024][1024] bf16
  float* amvl[3] = {amv0, amv1, amv2};

  dim3 blk(256);
  f32_to_bf16<<<2048, blk, 0, stream>>>(x,  xb,  2097152);
  f32_to_bf16<<<64,   blk, 0, stream>>>(W0, W0b, 65536);
  conv_w4<<<768, blk, 0, stream>>>(Wq, Wk, Wv, Wo, Wqb);
  bias_concat<<<1, blk, 0, stream>>>(bq, bk, bv, bqkv);
  adj_to_bits<<<128, blk, 0, stream>>>(adj, bitsg);
  nbr_build<<<4, blk, 0, stream>>>(bitsg, idxg, cntg);

  // input projection: h = x @ W0^T  (f32 + bf16)
  gemm_bt<false,false,true,true><<<dim3(2,64,1), blk, 0, stream>>>(
      xb, 256, 0, W0b, 256, 0, hbuf, hb, 256, 0, 256, nullptr, 0, nullptr);

  for (int l = 0; l < 3; ++l){
    // fused q|k|v projection: grid z selects weight section and C column offset
    gemm_bt<true,false,false,true><<<dim3(2,64,3), blk, 0, stream>>>(
        hb, 256, 0, Wqb + (long)l*65536, 256, 196608,
        nullptr, qkv, 768, 256, 256, bqkv + l*768, 256, nullptr);
    // sparse attention
    attn_sparse<<<dim3(256,8), blk, 0, stream>>>(qkv, ob, idxg, cntg, amvl[l]);
    // y = o @ Wo^T + bo (f32)
    gemm_bt<true,false,true,false><<<dim3(2,64,1), blk, 0, stream>>>(
        ob, 256, 0, Wob + (long)l*65536, 256, 0, ybuf, nullptr, 256, 0, 256,
        bo + l*256, 0, nullptr);
    // h = LN(h + y)
    ln_kernel<<<dim3(2048), blk, 0, stream>>>(
        hbuf, ybuf, hbuf, (l < 2 ? hb : nullptr), (l < 2 ? nullptr : outf),
        gm + l*256, bt + l*256);
    // sparse chain
    if (l == 1)
      sp_gemm1<<<dim3(1024,8), blk, 0, stream>>>(amv1, amv0, idxg, cntg, P1);
    if (l == 2)
      sp_gemm2<<<dim3(1024,8), blk, 0, stream>>>(amv2, P1, idxg, cntg, outat);
  }
}